// Round 16
// baseline (86.910 us; speedup 1.0000x reference)
//
#include <hip/hip_runtime.h>

#define NQ 10

#if __has_builtin(__builtin_amdgcn_permlane16_swap)
#define HAVE_PLSWAP 1
#endif

typedef float v2f __attribute__((ext_vector_type(2)));

// ================= compile-time GF(2) ring-frame machinery =================
struct M10 { unsigned r[10]; };

constexpr M10 mk_R() {
    M10 A{};
    A.r[0] = 0b1111111110u;
    for (int k = 1; k < 10; ++k) A.r[k] = (1u << (k + 1)) - 1u;
    return A;
}
constexpr M10 mk_Rinv() {
    M10 A{};
    A.r[0] = (1u << 0) | (1u << 9);
    A.r[1] = (1u << 0) | (1u << 1) | (1u << 9);
    for (int k = 2; k < 10; ++k) A.r[k] = (1u << (k - 1)) | (1u << k);
    return A;
}
constexpr M10 mmul(M10 A, M10 B) {
    M10 C{};
    for (int k = 0; k < 10; ++k) {
        unsigned v = 0;
        for (int j = 0; j < 10; ++j)
            if ((A.r[k] >> j) & 1u) v ^= B.r[j];
        C.r[k] = v;
    }
    return C;
}
constexpr M10 RF  = mk_R();
constexpr M10 RV  = mk_Rinv();
constexpr M10 RF2 = mmul(RF, RF);
constexpr M10 RF3 = mmul(RF2, RF);
constexpr M10 RF4 = mmul(RF2, RF2);
constexpr M10 RV2 = mmul(RV, RV);
constexpr M10 RV3 = mmul(RV2, RV);

constexpr bool isI(M10 A) {
    for (int k = 0; k < 10; ++k) if (A.r[k] != (1u << k)) return false;
    return true;
}
static_assert(isI(mmul(RF, RV)), "Rinv wrong");
static_assert(isI(mmul(RV3, RF3)), "powers wrong");

constexpr unsigned colq(M10 A, int q) {
    unsigned m = 0;
    for (int k = 0; k < 10; ++k) m |= ((A.r[k] >> q) & 1u) << k;
    return m;
}
constexpr int laneM(unsigned qm) {
    int m = 0;
    for (int q = 0; q <= 5; ++q) if ((qm >> q) & 1u) m |= 1 << (5 - q);
    return m;
}
constexpr int regM(unsigned qm) {
    int m = 0;
    for (int q = 6; q <= 9; ++q) if ((qm >> q) & 1u) m |= 1 << (9 - q);
    return m;
}

// ================= cross-lane: single-value exchange (readout only) ========
template<int CTRL>
__device__ __forceinline__ float dppmov(float v) {
    return __int_as_float(__builtin_amdgcn_mov_dpp(__float_as_int(v), CTRL, 0xF, 0xF, true));
}
template<int M>
__device__ __forceinline__ float lx(float v) {
    static_assert(M > 0 && M < 64, "mask");
    if constexpr (M == 1)       return dppmov<0xB1>(v);
    else if constexpr (M == 2)  return dppmov<0x4E>(v);
    else if constexpr (M == 3)  return dppmov<0x1B>(v);
    else if constexpr (M == 7)  return dppmov<0x141>(v);
    else if constexpr (M == 8)  return dppmov<0x128>(v);
    else if constexpr (M == 15) return dppmov<0x140>(v);
    else if constexpr (M == 4)  return lx<3>(lx<7>(v));
    else if constexpr (M == 5)  return lx<2>(lx<7>(v));
    else if constexpr (M == 6)  return lx<1>(lx<7>(v));
    else if constexpr (M == 9)  return lx<1>(lx<8>(v));
    else if constexpr (M == 10) return lx<2>(lx<8>(v));
    else if constexpr (M == 11) return lx<3>(lx<8>(v));
    else if constexpr (M == 12) return lx<3>(lx<15>(v));
    else if constexpr (M == 13) return lx<2>(lx<15>(v));
    else if constexpr (M == 14) return lx<1>(lx<15>(v));
    else if constexpr (M < 32)
        return __int_as_float(__builtin_amdgcn_ds_swizzle(__float_as_int(v), (M << 10) | 0x1F));
    else
        return __shfl_xor(v, M, 64);
}

// ===== pair exchange, pure VALU for ANY lane mask ≤63 =====
// xor_M = xor_{M&32} o xor_{M&16} o xor_{M&15}. High bits use the R6-verified
// DOUBLE permlane swap (direction-invariant, 1 instr/value); low bits DPP.
template<int M>
__device__ __forceinline__ void xchf(float& a, float& b) {
    static_assert(M > 0 && M < 64, "mask");
#ifdef HAVE_PLSWAP
    if constexpr ((M & 32) != 0) {
        auto r1 = __builtin_amdgcn_permlane32_swap(__float_as_uint(a), __float_as_uint(b), false, false);
        auto r2 = __builtin_amdgcn_permlane32_swap(r1[1], r1[0], false, false);
        a = __uint_as_float(r2[0]);
        b = __uint_as_float(r2[1]);
    }
    if constexpr ((M & 16) != 0) {
        auto r1 = __builtin_amdgcn_permlane16_swap(__float_as_uint(a), __float_as_uint(b), false, false);
        auto r2 = __builtin_amdgcn_permlane16_swap(r1[1], r1[0], false, false);
        a = __uint_as_float(r2[0]);
        b = __uint_as_float(r2[1]);
    }
    if constexpr ((M & 15) != 0) {
        a = lx<(M & 15) ? (M & 15) : 1>(a);
        b = lx<(M & 15) ? (M & 15) : 1>(b);
    }
#else
    a = lx<M>(a);
    b = lx<M>(b);
#endif
}
template<int M>
__device__ __forceinline__ void xchv(v2f& a, v2f& b) {
    float ax = a.x, bx = b.x, ay = a.y, by = b.y;
    xchf<M>(ax, bx);
    xchf<M>(ay, by);
    a.x = ax; a.y = ay; b.x = bx; b.y = by;
}

__device__ __forceinline__ v2f cmul(v2f a, v2f b) {
    v2f n; n.x = -a.y; n.y = a.y;
    return a.xx * b + n * b.yx;
}

// ============ generalized RY: flip (LM,RM), role (LW,RW) — all-VALU ========
template<int LM, int RM, int LW, int RW>
__device__ __forceinline__ void ry_g(v2f st[16], int lane, float c, float s) {
    static_assert((LM | RM) != 0, "null mask");
    const float baseP = (__builtin_popcount((unsigned)(lane & LW)) & 1) ? s : -s;
    if constexpr (RM == 0) {
        // pair consecutive regs so the permlane double-swap has its pair
#pragma unroll
        for (int r = 0; r < 16; r += 2) {
            v2f pa = st[r], pb = st[r + 1];
            xchv<LM ? LM : 1>(pa, pb);
            const float cB0 = (__builtin_popcount((unsigned)(r & RW)) & 1) ? -baseP : baseP;
            const float cB1 = (__builtin_popcount((unsigned)((r + 1) & RW)) & 1) ? -baseP : baseP;
            st[r]     = c * st[r]     + cB0 * pa;
            st[r + 1] = c * st[r + 1] + cB1 * pb;
        }
    } else {
        constexpr int PIV = RM & (-RM);
#pragma unroll
        for (int r = 0; r < 16; ++r) {
            if (r & PIV) continue;
            const int rb = r ^ RM;
            v2f ea = st[r], eb = st[rb];
            if constexpr (LM != 0) xchv<LM ? LM : 1>(ea, eb);
            // partner of t@r is exchanged st[rb] (= eb), and vice versa
            const float cBa = (__builtin_popcount((unsigned)(r & RW)) & 1) ? -baseP : baseP;
            const float cBb = (__builtin_popcount((unsigned)(rb & RW)) & 1) ? -baseP : baseP;
            st[r]  = c * st[r]  + cBa * eb;
            st[rb] = c * st[rb] + cBb * ea;
        }
    }
}

// ============ generalized fused Z-diagonal at frame R^L ============
template<int L>
__device__ __forceinline__ void diag_g(v2f st[16], int lane, const float* pl) {
    constexpr M10 W = (L == 1) ? RF : RF2;
    float G[16];
#pragma unroll
    for (int i = 0; i < 16; ++i) G[i] = 0.f;
#pragma unroll
    for (int q = 0; q < 10; ++q) {
        const int LWq = laneM(W.r[q]);
        const int RWq = regM(W.r[q]);
        const float hz = 0.5f * pl[10 + q];
        const float gq = (__builtin_popcount((unsigned)(lane & LWq)) & 1) ? hz : -hz;
        G[RWq] += gq;
    }
#pragma unroll
    for (int m = 1; m < 16; m <<= 1) {
#pragma unroll
        for (int r = 0; r < 16; ++r) {
            if (r & m) continue;
            const float a = G[r], bb = G[r | m];
            G[r] = a + bb;
            G[r | m] = a - bb;
        }
    }
#pragma unroll
    for (int r = 0; r < 16; ++r) {
        float sn, cs;
        __sincosf(G[r], &sn, &cs);
        v2f d; d.x = cs; d.y = sn;
        st[r] = cmul(st[r], d);
    }
}

__device__ __forceinline__ float wht64(float v, int lane) {
    float t;
    t = lx<1>(v);  v = (lane & 1)  ? (t - v) : (v + t);
    t = lx<2>(v);  v = (lane & 2)  ? (t - v) : (v + t);
    t = lx<4>(v);  v = (lane & 4)  ? (t - v) : (v + t);
    t = lx<8>(v);  v = (lane & 8)  ? (t - v) : (v + t);
    t = lx<16>(v); v = (lane & 16) ? (t - v) : (v + t);
    t = lx<32>(v); v = (lane & 32) ? (t - v) : (v + t);
    return v;
}

// ================= main kernel: one wave per batch sample =================
// Stored label t: lane bits = qubits 0..5 (masks 32..1), reg bits = qubits
// 6..9 (masks 8..1). Rings never applied — frame-tracked via R^l. All gate
// exchanges are VALU (DPP + permlane double-swap); ds only in readout WHT.
__global__ __launch_bounds__(256)
void pqc_kernel(const float* __restrict__ x,
                const float* __restrict__ params,
                float* __restrict__ out, int B) {
    const int lane = threadIdx.x & 63;
    const int wave = threadIdx.x >> 6;
    const int b = blockIdx.x * 4 + wave;
    if (b >= B) return;

    // ---- encoding + ENTIRE layer 0 (RY+RZ) folded into a product state ----
    const float* xb = x + (long)b * NQ;
    const float* p0 = params;
    float a[10], bb[10], cz[10], sz[10];
#pragma unroll
    for (int q = 0; q < 10; ++q) {
        __sincosf(0.5f * (xb[q] + p0[q]), &bb[q], &a[q]);
        __sincosf(0.5f * p0[10 + q], &sz[q], &cz[q]);
    }

    float R = 1.f;
    v2f P; P.x = 1.f; P.y = 0.f;
#pragma unroll
    for (int q = 0; q <= 5; ++q) {
        const int m = 1 << (5 - q);
        R *= (lane & m) ? bb[q] : a[q];
        v2f t; t.x = cz[q]; t.y = (lane & m) ? sz[q] : -sz[q];
        P = cmul(P, t);
    }
    v2f laneC = R * P;

    v2f u[4][2];
#pragma unroll
    for (int q = 6; q <= 9; ++q) {
        u[q - 6][0].x = a[q] * cz[q];  u[q - 6][0].y = -a[q] * sz[q];
        u[q - 6][1].x = bb[q] * cz[q]; u[q - 6][1].y =  bb[q] * sz[q];
    }
    v2f A2[4], B2[4];
#pragma unroll
    for (int k = 0; k < 4; ++k) {
        A2[k] = cmul(u[0][k >> 1], u[1][k & 1]);
        B2[k] = cmul(u[2][k >> 1], u[3][k & 1]);
    }
    v2f LA[4] = { cmul(laneC, A2[0]), cmul(laneC, A2[1]),
                  cmul(laneC, A2[2]), cmul(laneC, A2[3]) };

    v2f st[16];
#pragma unroll
    for (int r = 0; r < 16; ++r) st[r] = cmul(LA[r >> 2], B2[r & 3]);
    // layer-0 ring virtual: F = R from here on

#define GATE(INV, ROLE, Q, ANG) do { \
    float gc_, gs_; __sincosf(0.5f * (ANG), &gs_, &gc_); \
    ry_g<laneM(colq(INV, Q)), regM(colq(INV, Q)), \
         laneM(ROLE.r[Q]), regM(ROLE.r[Q])>(st, lane, gc_, gs_); \
} while (0)

    // ---- layer 1 (frame F = R) ----
    {
        const float* pl = params + 20;
        GATE(RV, RF, 0, pl[0]); GATE(RV, RF, 1, pl[1]);
        GATE(RV, RF, 2, pl[2]); GATE(RV, RF, 3, pl[3]);
        GATE(RV, RF, 4, pl[4]); GATE(RV, RF, 5, pl[5]);
        GATE(RV, RF, 6, pl[6]); GATE(RV, RF, 7, pl[7]);
        GATE(RV, RF, 8, pl[8]); GATE(RV, RF, 9, pl[9]);
        diag_g<1>(st, lane, pl);
    }
    // ---- layer 2 (frame F = R^2) ----
    {
        const float* pl = params + 40;
        GATE(RV2, RF2, 0, pl[0]); GATE(RV2, RF2, 1, pl[1]);
        GATE(RV2, RF2, 2, pl[2]); GATE(RV2, RF2, 3, pl[3]);
        GATE(RV2, RF2, 4, pl[4]); GATE(RV2, RF2, 5, pl[5]);
        GATE(RV2, RF2, 6, pl[6]); GATE(RV2, RF2, 7, pl[7]);
        GATE(RV2, RF2, 8, pl[8]); GATE(RV2, RF2, 9, pl[9]);
        diag_g<2>(st, lane, pl);
    }
    // ---- layer 3 (frame F = R^3; diag+final ring fold into readout) ----
    {
        const float* pl = params + 60;
        GATE(RV3, RF3, 0, pl[0]); GATE(RV3, RF3, 1, pl[1]);
        GATE(RV3, RF3, 2, pl[2]); GATE(RV3, RF3, 3, pl[3]);
        GATE(RV3, RF3, 4, pl[4]); GATE(RV3, RF3, 5, pl[5]);
        GATE(RV3, RF3, 6, pl[6]); GATE(RV3, RF3, 7, pl[7]);
        GATE(RV3, RF3, 8, pl[8]); GATE(RV3, RF3, 9, pl[9]);
    }
#undef GATE

    // ---- readout: <Z_q> with roles = rows of R^4 ----
    float p[16];
#pragma unroll
    for (int r = 0; r < 16; ++r)
        p[r] = st[r].x * st[r].x + st[r].y * st[r].y;
#pragma unroll
    for (int m = 1; m < 16; m <<= 1) {
#pragma unroll
        for (int r = 0; r < 16; ++r) {
            if (r & m) continue;
            const float a1 = p[r], b1 = p[r | m];
            p[r] = a1 + b1;
            p[r | m] = a1 - b1;
        }
    }
    const long base = (long)b * NQ;
#pragma unroll
    for (int q = 0; q < 10; ++q) {
        const int LWq = laneM(RF4.r[q]);
        const int RWq = regM(RF4.r[q]);
        const float v = wht64(p[RWq], lane);
        if (lane == LWq) out[base + q] = v;
    }
}

extern "C" void kernel_launch(void* const* d_in, const int* in_sizes, int n_in,
                              void* d_out, int out_size, void* d_ws, size_t ws_size,
                              hipStream_t stream) {
    const float* x = (const float*)d_in[0];       // [B, 10]
    const float* params = (const float*)d_in[1];  // [4, 20]
    float* out = (float*)d_out;                   // [B, 10]
    const int B = in_sizes[0] / NQ;               // 4096
    const int grid = (B + 3) / 4;                 // 4 waves (samples) per block
    pqc_kernel<<<grid, 256, 0, stream>>>(x, params, out, B);
}

// Round 17
// 78.555 us; speedup vs baseline: 1.1064x; 1.1064x over previous
//
#include <hip/hip_runtime.h>

#define NQ 10

typedef float v2f __attribute__((ext_vector_type(2)));

// ================= compile-time GF(2) ring-frame machinery =================
struct M10 { unsigned r[10]; };

constexpr M10 mk_R() {
    M10 A{};
    A.r[0] = 0b1111111110u;
    for (int k = 1; k < 10; ++k) A.r[k] = (1u << (k + 1)) - 1u;
    return A;
}
constexpr M10 mk_Rinv() {
    M10 A{};
    A.r[0] = (1u << 0) | (1u << 9);
    A.r[1] = (1u << 0) | (1u << 1) | (1u << 9);
    for (int k = 2; k < 10; ++k) A.r[k] = (1u << (k - 1)) | (1u << k);
    return A;
}
constexpr M10 mmul(M10 A, M10 B) {
    M10 C{};
    for (int k = 0; k < 10; ++k) {
        unsigned v = 0;
        for (int j = 0; j < 10; ++j)
            if ((A.r[k] >> j) & 1u) v ^= B.r[j];
        C.r[k] = v;
    }
    return C;
}
constexpr M10 RF  = mk_R();
constexpr M10 RV  = mk_Rinv();
constexpr M10 RF2 = mmul(RF, RF);
constexpr M10 RF3 = mmul(RF2, RF);
constexpr M10 RF4 = mmul(RF2, RF2);
constexpr M10 RV2 = mmul(RV, RV);
constexpr M10 RV3 = mmul(RV2, RV);

constexpr bool isI(M10 A) {
    for (int k = 0; k < 10; ++k) if (A.r[k] != (1u << k)) return false;
    return true;
}
static_assert(isI(mmul(RF, RV)), "Rinv wrong");
static_assert(isI(mmul(RV3, RF3)), "powers wrong");

constexpr unsigned colq(M10 A, int q) {
    unsigned m = 0;
    for (int k = 0; k < 10; ++k) m |= ((A.r[k] >> q) & 1u) << k;
    return m;
}
constexpr int laneM(unsigned qm) {
    int m = 0;
    for (int q = 0; q <= 5; ++q) if ((qm >> q) & 1u) m |= 1 << (5 - q);
    return m;
}
constexpr int regM(unsigned qm) {
    int m = 0;
    for (int q = 6; q <= 9; ++q) if ((qm >> q) & 1u) m |= 1 << (9 - q);
    return m;
}

// ================= cross-lane exchange: value from lane^M =================
// Pipe policy (R16 lesson: VALU is the critical pipe, ds has slack):
//   single-DPP masks 1,2,3,7,8,15 -> VALU DPP (1 op)
//   everything else < 32          -> ONE ds_swizzle (ds pipe, overlapped)
//   >= 32                         -> __shfl_xor (ds_bpermute)
template<int CTRL>
__device__ __forceinline__ float dppmov(float v) {
    return __int_as_float(__builtin_amdgcn_mov_dpp(__float_as_int(v), CTRL, 0xF, 0xF, true));
}
template<int M>
__device__ __forceinline__ float lx(float v) {
    static_assert(M > 0 && M < 64, "mask");
    if constexpr (M == 1)       return dppmov<0xB1>(v);
    else if constexpr (M == 2)  return dppmov<0x4E>(v);
    else if constexpr (M == 3)  return dppmov<0x1B>(v);
    else if constexpr (M == 7)  return dppmov<0x141>(v);
    else if constexpr (M == 8)  return dppmov<0x128>(v);
    else if constexpr (M == 15) return dppmov<0x140>(v);
    else if constexpr (M < 32)
        return __int_as_float(__builtin_amdgcn_ds_swizzle(__float_as_int(v), (M << 10) | 0x1F));
    else
        return __shfl_xor(v, M, 64);
}

__device__ __forceinline__ v2f cmul(v2f a, v2f b) {
    v2f n; n.x = -a.y; n.y = a.y;
    return a.xx * b + n * b.yx;
}

// ============ generalized RY: flip (LM,RM), role (LW,RW) ============
template<int LM, int RM, int LW, int RW>
__device__ __forceinline__ void ry_g(v2f st[16], int lane, float c, float s) {
    static_assert((LM | RM) != 0, "null mask");
    const float baseP = (__builtin_popcount((unsigned)(lane & LW)) & 1) ? s : -s;
    if constexpr (RM == 0) {
#pragma unroll
        for (int r = 0; r < 16; ++r) {
            v2f part;
            part.x = lx<LM ? LM : 1>(st[r].x);
            part.y = lx<LM ? LM : 1>(st[r].y);
            const float cB = (__builtin_popcount((unsigned)(r & RW)) & 1) ? -baseP : baseP;
            st[r] = c * st[r] + cB * part;
        }
    } else {
        constexpr int PIV = RM & (-RM);
#pragma unroll
        for (int r = 0; r < 16; ++r) {
            if (r & PIV) continue;
            const int rb = r ^ RM;
            v2f ea, eb;
            if constexpr (LM != 0) {
                ea.x = lx<LM ? LM : 1>(st[r].x);  ea.y = lx<LM ? LM : 1>(st[r].y);
                eb.x = lx<LM ? LM : 1>(st[rb].x); eb.y = lx<LM ? LM : 1>(st[rb].y);
            } else {
                ea = st[r]; eb = st[rb];
            }
            const float cBa = (__builtin_popcount((unsigned)(r & RW)) & 1) ? -baseP : baseP;
            const float cBb = (__builtin_popcount((unsigned)(rb & RW)) & 1) ? -baseP : baseP;
            st[r]  = c * st[r]  + cBa * eb;
            st[rb] = c * st[rb] + cBb * ea;
        }
    }
}

// ============ generalized fused Z-diagonal at frame R^L ============
template<int L>
__device__ __forceinline__ void diag_g(v2f st[16], int lane, const float* pl) {
    constexpr M10 W = (L == 1) ? RF : RF2;
    float G[16];
#pragma unroll
    for (int i = 0; i < 16; ++i) G[i] = 0.f;
#pragma unroll
    for (int q = 0; q < 10; ++q) {
        const int LWq = laneM(W.r[q]);
        const int RWq = regM(W.r[q]);
        const float hz = 0.5f * pl[10 + q];
        const float gq = (__builtin_popcount((unsigned)(lane & LWq)) & 1) ? hz : -hz;
        G[RWq] += gq;
    }
#pragma unroll
    for (int m = 1; m < 16; m <<= 1) {
#pragma unroll
        for (int r = 0; r < 16; ++r) {
            if (r & m) continue;
            const float a = G[r], bb = G[r | m];
            G[r] = a + bb;
            G[r | m] = a - bb;
        }
    }
#pragma unroll
    for (int r = 0; r < 16; ++r) {
        float sn, cs;
        __sincosf(G[r], &sn, &cs);
        v2f d; d.x = cs; d.y = sn;
        st[r] = cmul(st[r], d);
    }
}

__device__ __forceinline__ float wht64(float v, int lane) {
    float t;
    t = lx<1>(v);  v = (lane & 1)  ? (t - v) : (v + t);
    t = lx<2>(v);  v = (lane & 2)  ? (t - v) : (v + t);
    t = lx<4>(v);  v = (lane & 4)  ? (t - v) : (v + t);
    t = lx<8>(v);  v = (lane & 8)  ? (t - v) : (v + t);
    t = lx<16>(v); v = (lane & 16) ? (t - v) : (v + t);
    t = lx<32>(v); v = (lane & 32) ? (t - v) : (v + t);
    return v;
}

// readout dedup: distinct reg-bins of RF4 rows, computed constexpr
struct RBins {
    int nbins;
    int bin[10];    // distinct RWq values
    int q2bin[10];  // per-output index into bin[]
};
constexpr RBins mk_rbins() {
    RBins R{};
    R.nbins = 0;
    for (int q = 0; q < 10; ++q) {
        const int rw = regM(RF4.r[q]);
        int f = -1;
        for (int i = 0; i < R.nbins; ++i) if (R.bin[i] == rw) { f = i; break; }
        if (f < 0) { f = R.nbins; R.bin[R.nbins++] = rw; }
        R.q2bin[q] = f;
    }
    return R;
}
constexpr RBins RB = mk_rbins();

// ================= main kernel: one wave per batch sample =================
// Stored label t: lane bits = qubits 0..5 (masks 32..1), reg bits = qubits
// 6..9 (masks 8..1). Rings never applied — frame-tracked via R^l.
__global__ __launch_bounds__(256)
void pqc_kernel(const float* __restrict__ x,
                const float* __restrict__ params,
                float* __restrict__ out, int B) {
    const int lane = threadIdx.x & 63;
    const int wave = threadIdx.x >> 6;
    const int b = blockIdx.x * 4 + wave;
    if (b >= B) return;

    // ---- encoding + ENTIRE layer 0 (RY+RZ) folded into a product state ----
    const float* xb = x + (long)b * NQ;
    const float* p0 = params;
    float a[10], bb[10], cz[10], sz[10];
#pragma unroll
    for (int q = 0; q < 10; ++q) {
        __sincosf(0.5f * (xb[q] + p0[q]), &bb[q], &a[q]);
        __sincosf(0.5f * p0[10 + q], &sz[q], &cz[q]);
    }

    float R = 1.f;
    v2f P; P.x = 1.f; P.y = 0.f;
#pragma unroll
    for (int q = 0; q <= 5; ++q) {
        const int m = 1 << (5 - q);
        R *= (lane & m) ? bb[q] : a[q];
        v2f t; t.x = cz[q]; t.y = (lane & m) ? sz[q] : -sz[q];
        P = cmul(P, t);
    }
    v2f laneC = R * P;

    v2f u[4][2];
#pragma unroll
    for (int q = 6; q <= 9; ++q) {
        u[q - 6][0].x = a[q] * cz[q];  u[q - 6][0].y = -a[q] * sz[q];
        u[q - 6][1].x = bb[q] * cz[q]; u[q - 6][1].y =  bb[q] * sz[q];
    }
    v2f A2[4], B2[4];
#pragma unroll
    for (int k = 0; k < 4; ++k) {
        A2[k] = cmul(u[0][k >> 1], u[1][k & 1]);
        B2[k] = cmul(u[2][k >> 1], u[3][k & 1]);
    }
    v2f LA[4] = { cmul(laneC, A2[0]), cmul(laneC, A2[1]),
                  cmul(laneC, A2[2]), cmul(laneC, A2[3]) };

    v2f st[16];
#pragma unroll
    for (int r = 0; r < 16; ++r) st[r] = cmul(LA[r >> 2], B2[r & 3]);
    // layer-0 ring virtual: F = R from here on

#define GATE(INV, ROLE, Q, ANG) do { \
    float gc_, gs_; __sincosf(0.5f * (ANG), &gs_, &gc_); \
    ry_g<laneM(colq(INV, Q)), regM(colq(INV, Q)), \
         laneM(ROLE.r[Q]), regM(ROLE.r[Q])>(st, lane, gc_, gs_); \
} while (0)

    // ---- layer 1 (frame F = R) ----
    {
        const float* pl = params + 20;
        GATE(RV, RF, 0, pl[0]); GATE(RV, RF, 1, pl[1]);
        GATE(RV, RF, 2, pl[2]); GATE(RV, RF, 3, pl[3]);
        GATE(RV, RF, 4, pl[4]); GATE(RV, RF, 5, pl[5]);
        GATE(RV, RF, 6, pl[6]); GATE(RV, RF, 7, pl[7]);
        GATE(RV, RF, 8, pl[8]); GATE(RV, RF, 9, pl[9]);
        diag_g<1>(st, lane, pl);
    }
    // ---- layer 2 (frame F = R^2) ----
    {
        const float* pl = params + 40;
        GATE(RV2, RF2, 0, pl[0]); GATE(RV2, RF2, 1, pl[1]);
        GATE(RV2, RF2, 2, pl[2]); GATE(RV2, RF2, 3, pl[3]);
        GATE(RV2, RF2, 4, pl[4]); GATE(RV2, RF2, 5, pl[5]);
        GATE(RV2, RF2, 6, pl[6]); GATE(RV2, RF2, 7, pl[7]);
        GATE(RV2, RF2, 8, pl[8]); GATE(RV2, RF2, 9, pl[9]);
        diag_g<2>(st, lane, pl);
    }
    // ---- layer 3 (frame F = R^3; diag+final ring fold into readout) ----
    {
        const float* pl = params + 60;
        GATE(RV3, RF3, 0, pl[0]); GATE(RV3, RF3, 1, pl[1]);
        GATE(RV3, RF3, 2, pl[2]); GATE(RV3, RF3, 3, pl[3]);
        GATE(RV3, RF3, 4, pl[4]); GATE(RV3, RF3, 5, pl[5]);
        GATE(RV3, RF3, 6, pl[6]); GATE(RV3, RF3, 7, pl[7]);
        GATE(RV3, RF3, 8, pl[8]); GATE(RV3, RF3, 9, pl[9]);
    }
#undef GATE

    // ---- readout: <Z_q> with roles = rows of R^4 ----
    float p[16];
#pragma unroll
    for (int r = 0; r < 16; ++r)
        p[r] = st[r].x * st[r].x + st[r].y * st[r].y;
#pragma unroll
    for (int m = 1; m < 16; m <<= 1) {
#pragma unroll
        for (int r = 0; r < 16; ++r) {
            if (r & m) continue;
            const float a1 = p[r], b1 = p[r | m];
            p[r] = a1 + b1;
            p[r | m] = a1 - b1;
        }
    }
    // one wht64 per DISTINCT reg-bin (constexpr dedup), then per-output pick
    float wv[RB.nbins > 0 ? 10 : 1];
#pragma unroll
    for (int i = 0; i < RB.nbins; ++i)
        wv[i] = wht64(p[RB.bin[i]], lane);
    const long base = (long)b * NQ;
#pragma unroll
    for (int q = 0; q < 10; ++q) {
        const int LWq = laneM(RF4.r[q]);
        if (lane == LWq) out[base + q] = wv[RB.q2bin[q]];
    }
}

extern "C" void kernel_launch(void* const* d_in, const int* in_sizes, int n_in,
                              void* d_out, int out_size, void* d_ws, size_t ws_size,
                              hipStream_t stream) {
    const float* x = (const float*)d_in[0];       // [B, 10]
    const float* params = (const float*)d_in[1];  // [4, 20]
    float* out = (float*)d_out;                   // [B, 10]
    const int B = in_sizes[0] / NQ;               // 4096
    const int grid = (B + 3) / 4;                 // 4 waves (samples) per block
    pqc_kernel<<<grid, 256, 0, stream>>>(x, params, out, B);
}

// Round 18
// 78.419 us; speedup vs baseline: 1.1083x; 1.0017x over previous
//
#include <hip/hip_runtime.h>

#define NQ 10

typedef float v2f __attribute__((ext_vector_type(2)));

// ================= compile-time GF(2) ring-frame machinery =================
struct M10 { unsigned r[10]; };

constexpr M10 mk_R() {
    M10 A{};
    A.r[0] = 0b1111111110u;
    for (int k = 1; k < 10; ++k) A.r[k] = (1u << (k + 1)) - 1u;
    return A;
}
constexpr M10 mk_Rinv() {
    M10 A{};
    A.r[0] = (1u << 0) | (1u << 9);
    A.r[1] = (1u << 0) | (1u << 1) | (1u << 9);
    for (int k = 2; k < 10; ++k) A.r[k] = (1u << (k - 1)) | (1u << k);
    return A;
}
constexpr M10 mmul(M10 A, M10 B) {
    M10 C{};
    for (int k = 0; k < 10; ++k) {
        unsigned v = 0;
        for (int j = 0; j < 10; ++j)
            if ((A.r[k] >> j) & 1u) v ^= B.r[j];
        C.r[k] = v;
    }
    return C;
}
constexpr M10 RF  = mk_R();
constexpr M10 RV  = mk_Rinv();
constexpr M10 RF2 = mmul(RF, RF);
constexpr M10 RF3 = mmul(RF2, RF);
constexpr M10 RF4 = mmul(RF2, RF2);
constexpr M10 RV2 = mmul(RV, RV);
constexpr M10 RV3 = mmul(RV2, RV);

constexpr bool isI(M10 A) {
    for (int k = 0; k < 10; ++k) if (A.r[k] != (1u << k)) return false;
    return true;
}
static_assert(isI(mmul(RF, RV)), "Rinv wrong");
static_assert(isI(mmul(RV3, RF3)), "powers wrong");

constexpr unsigned colq(M10 A, int q) {
    unsigned m = 0;
    for (int k = 0; k < 10; ++k) m |= ((A.r[k] >> q) & 1u) << k;
    return m;
}
constexpr int laneM(unsigned qm) {
    int m = 0;
    for (int q = 0; q <= 5; ++q) if ((qm >> q) & 1u) m |= 1 << (5 - q);
    return m;
}
constexpr int regM(unsigned qm) {
    int m = 0;
    for (int q = 6; q <= 9; ++q) if ((qm >> q) & 1u) m |= 1 << (9 - q);
    return m;
}

// ================= cross-lane exchange: value from lane^M =================
// R14/R17 A-B result: best mix is 1-DPP masks on VALU, 2-DPP chains for
// mid masks (still VALU, zero-latency), ds_swizzle only for 16..31, shfl >=32.
template<int CTRL>
__device__ __forceinline__ float dppmov(float v) {
    return __int_as_float(__builtin_amdgcn_mov_dpp(__float_as_int(v), CTRL, 0xF, 0xF, true));
}
template<int M>
__device__ __forceinline__ float lx(float v) {
    static_assert(M > 0 && M < 64, "mask");
    if constexpr (M == 1)       return dppmov<0xB1>(v);
    else if constexpr (M == 2)  return dppmov<0x4E>(v);
    else if constexpr (M == 3)  return dppmov<0x1B>(v);
    else if constexpr (M == 7)  return dppmov<0x141>(v);
    else if constexpr (M == 8)  return dppmov<0x128>(v);
    else if constexpr (M == 15) return dppmov<0x140>(v);
    else if constexpr (M == 4)  return lx<3>(lx<7>(v));
    else if constexpr (M == 5)  return lx<2>(lx<7>(v));
    else if constexpr (M == 6)  return lx<1>(lx<7>(v));
    else if constexpr (M == 9)  return lx<1>(lx<8>(v));
    else if constexpr (M == 10) return lx<2>(lx<8>(v));
    else if constexpr (M == 11) return lx<3>(lx<8>(v));
    else if constexpr (M == 12) return lx<3>(lx<15>(v));
    else if constexpr (M == 13) return lx<2>(lx<15>(v));
    else if constexpr (M == 14) return lx<1>(lx<15>(v));
    else if constexpr (M < 32)
        return __int_as_float(__builtin_amdgcn_ds_swizzle(__float_as_int(v), (M << 10) | 0x1F));
    else
        return __shfl_xor(v, M, 64);
}

__device__ __forceinline__ v2f cmul(v2f a, v2f b) {
    v2f n; n.x = -a.y; n.y = a.y;
    return a.xx * b + n * b.yx;
}

// ====== generalized RY on TWO interleaved states (shared angles, ILP=2) ======
template<int LM, int RM, int LW, int RW>
__device__ __forceinline__ void ry_g2(v2f sa[16], v2f sb[16], int lane, float c, float s) {
    static_assert((LM | RM) != 0, "null mask");
    const float baseP = (__builtin_popcount((unsigned)(lane & LW)) & 1) ? s : -s;
    if constexpr (RM == 0) {
#pragma unroll
        for (int r = 0; r < 16; ++r) {
            v2f pa, pb;
            pa.x = lx<LM ? LM : 1>(sa[r].x); pa.y = lx<LM ? LM : 1>(sa[r].y);
            pb.x = lx<LM ? LM : 1>(sb[r].x); pb.y = lx<LM ? LM : 1>(sb[r].y);
            const float cB = (__builtin_popcount((unsigned)(r & RW)) & 1) ? -baseP : baseP;
            sa[r] = c * sa[r] + cB * pa;
            sb[r] = c * sb[r] + cB * pb;
        }
    } else {
        constexpr int PIV = RM & (-RM);
#pragma unroll
        for (int r = 0; r < 16; ++r) {
            if (r & PIV) continue;
            const int rb = r ^ RM;
            v2f eaA, ebA, eaB, ebB;
            if constexpr (LM != 0) {
                eaA.x = lx<LM ? LM : 1>(sa[r].x);  eaA.y = lx<LM ? LM : 1>(sa[r].y);
                ebA.x = lx<LM ? LM : 1>(sa[rb].x); ebA.y = lx<LM ? LM : 1>(sa[rb].y);
                eaB.x = lx<LM ? LM : 1>(sb[r].x);  eaB.y = lx<LM ? LM : 1>(sb[r].y);
                ebB.x = lx<LM ? LM : 1>(sb[rb].x); ebB.y = lx<LM ? LM : 1>(sb[rb].y);
            } else {
                eaA = sa[r]; ebA = sa[rb]; eaB = sb[r]; ebB = sb[rb];
            }
            const float cBa = (__builtin_popcount((unsigned)(r & RW)) & 1) ? -baseP : baseP;
            const float cBb = (__builtin_popcount((unsigned)(rb & RW)) & 1) ? -baseP : baseP;
            sa[r]  = c * sa[r]  + cBa * ebA;
            sa[rb] = c * sa[rb] + cBb * eaA;
            sb[r]  = c * sb[r]  + cBa * ebB;
            sb[rb] = c * sb[rb] + cBb * eaB;
        }
    }
}

// ====== generalized fused Z-diagonal at frame R^L, two states ======
template<int L>
__device__ __forceinline__ void diag_g2(v2f sa[16], v2f sb[16], int lane, const float* pl) {
    constexpr M10 W = (L == 1) ? RF : RF2;
    float G[16];
#pragma unroll
    for (int i = 0; i < 16; ++i) G[i] = 0.f;
#pragma unroll
    for (int q = 0; q < 10; ++q) {
        const int LWq = laneM(W.r[q]);
        const int RWq = regM(W.r[q]);
        const float hz = 0.5f * pl[10 + q];
        const float gq = (__builtin_popcount((unsigned)(lane & LWq)) & 1) ? hz : -hz;
        G[RWq] += gq;
    }
#pragma unroll
    for (int m = 1; m < 16; m <<= 1) {
#pragma unroll
        for (int r = 0; r < 16; ++r) {
            if (r & m) continue;
            const float a = G[r], bb = G[r | m];
            G[r] = a + bb;
            G[r | m] = a - bb;
        }
    }
#pragma unroll
    for (int r = 0; r < 16; ++r) {
        float sn, cs;
        __sincosf(G[r], &sn, &cs);
        v2f d; d.x = cs; d.y = sn;
        sa[r] = cmul(sa[r], d);
        sb[r] = cmul(sb[r], d);
    }
}

__device__ __forceinline__ float wht64(float v, int lane) {
    float t;
    t = lx<1>(v);  v = (lane & 1)  ? (t - v) : (v + t);
    t = lx<2>(v);  v = (lane & 2)  ? (t - v) : (v + t);
    t = lx<4>(v);  v = (lane & 4)  ? (t - v) : (v + t);
    t = lx<8>(v);  v = (lane & 8)  ? (t - v) : (v + t);
    t = lx<16>(v); v = (lane & 16) ? (t - v) : (v + t);
    t = lx<32>(v); v = (lane & 32) ? (t - v) : (v + t);
    return v;
}

// readout dedup: distinct reg-bins of RF4 rows, computed constexpr
struct RBins {
    int nbins;
    int bin[10];
    int q2bin[10];
};
constexpr RBins mk_rbins() {
    RBins R{};
    R.nbins = 0;
    for (int q = 0; q < 10; ++q) {
        const int rw = regM(RF4.r[q]);
        int f = -1;
        for (int i = 0; i < R.nbins; ++i) if (R.bin[i] == rw) { f = i; break; }
        if (f < 0) { f = R.nbins; R.bin[R.nbins++] = rw; }
        R.q2bin[q] = f;
    }
    return R;
}
constexpr RBins RB = mk_rbins();

// ====== encode one sample's product state (enc + full layer 0 folded) ======
__device__ __forceinline__ void encode_state(const float* xb, const float* p0,
                                             const float* czt, const float* szt,
                                             int lane, v2f st[16]) {
    float a[10], bb[10];
#pragma unroll
    for (int q = 0; q < 10; ++q)
        __sincosf(0.5f * (xb[q] + p0[q]), &bb[q], &a[q]);

    float R = 1.f;
    v2f P; P.x = 1.f; P.y = 0.f;
#pragma unroll
    for (int q = 0; q <= 5; ++q) {
        const int m = 1 << (5 - q);
        R *= (lane & m) ? bb[q] : a[q];
        v2f t; t.x = czt[q]; t.y = (lane & m) ? szt[q] : -szt[q];
        P = cmul(P, t);
    }
    v2f laneC = R * P;

    v2f u[4][2];
#pragma unroll
    for (int q = 6; q <= 9; ++q) {
        u[q - 6][0].x = a[q] * czt[q];  u[q - 6][0].y = -a[q] * szt[q];
        u[q - 6][1].x = bb[q] * czt[q]; u[q - 6][1].y =  bb[q] * szt[q];
    }
    v2f A2[4], B2[4];
#pragma unroll
    for (int k = 0; k < 4; ++k) {
        A2[k] = cmul(u[0][k >> 1], u[1][k & 1]);
        B2[k] = cmul(u[2][k >> 1], u[3][k & 1]);
    }
    v2f LA[4] = { cmul(laneC, A2[0]), cmul(laneC, A2[1]),
                  cmul(laneC, A2[2]), cmul(laneC, A2[3]) };
#pragma unroll
    for (int r = 0; r < 16; ++r) st[r] = cmul(LA[r >> 2], B2[r & 3]);
}

// ================= main kernel: one wave per TWO batch samples =================
// Stored label t: lane bits = qubits 0..5 (masks 32..1), reg bits = qubits
// 6..9 (masks 8..1). Rings frame-tracked (never applied). Angles/tables are
// sample-independent -> shared across the wave's two samples; the two state
// chains are independent -> ILP hides exchange latency.
__global__ __launch_bounds__(256, 2)
void pqc_kernel(const float* __restrict__ x,
                const float* __restrict__ params,
                float* __restrict__ out, int B) {
    const int lane = threadIdx.x & 63;
    const int wid = threadIdx.x >> 6;
    const int b0 = blockIdx.x * 8 + wid * 2;   // this wave: samples b0, b0+1
    if (b0 >= B) return;

    const float* p0 = params;
    float czt[10], szt[10];
#pragma unroll
    for (int q = 0; q < 10; ++q)
        __sincosf(0.5f * p0[10 + q], &szt[q], &czt[q]);

    v2f sa[16], sb[16];
    encode_state(x + (long)b0 * NQ, p0, czt, szt, lane, sa);
    encode_state(x + (long)(b0 + 1) * NQ, p0, czt, szt, lane, sb);
    // layer-0 ring virtual: F = R from here

#define GATE(INV, ROLE, Q, ANG) do { \
    float gc_, gs_; __sincosf(0.5f * (ANG), &gs_, &gc_); \
    ry_g2<laneM(colq(INV, Q)), regM(colq(INV, Q)), \
          laneM(ROLE.r[Q]), regM(ROLE.r[Q])>(sa, sb, lane, gc_, gs_); \
} while (0)

    // ---- layer 1 (frame F = R) ----
    {
        const float* pl = params + 20;
        GATE(RV, RF, 0, pl[0]); GATE(RV, RF, 1, pl[1]);
        GATE(RV, RF, 2, pl[2]); GATE(RV, RF, 3, pl[3]);
        GATE(RV, RF, 4, pl[4]); GATE(RV, RF, 5, pl[5]);
        GATE(RV, RF, 6, pl[6]); GATE(RV, RF, 7, pl[7]);
        GATE(RV, RF, 8, pl[8]); GATE(RV, RF, 9, pl[9]);
        diag_g2<1>(sa, sb, lane, pl);
    }
    // ---- layer 2 (frame F = R^2) ----
    {
        const float* pl = params + 40;
        GATE(RV2, RF2, 0, pl[0]); GATE(RV2, RF2, 1, pl[1]);
        GATE(RV2, RF2, 2, pl[2]); GATE(RV2, RF2, 3, pl[3]);
        GATE(RV2, RF2, 4, pl[4]); GATE(RV2, RF2, 5, pl[5]);
        GATE(RV2, RF2, 6, pl[6]); GATE(RV2, RF2, 7, pl[7]);
        GATE(RV2, RF2, 8, pl[8]); GATE(RV2, RF2, 9, pl[9]);
        diag_g2<2>(sa, sb, lane, pl);
    }
    // ---- layer 3 (frame F = R^3; diag+final ring fold into readout) ----
    {
        const float* pl = params + 60;
        GATE(RV3, RF3, 0, pl[0]); GATE(RV3, RF3, 1, pl[1]);
        GATE(RV3, RF3, 2, pl[2]); GATE(RV3, RF3, 3, pl[3]);
        GATE(RV3, RF3, 4, pl[4]); GATE(RV3, RF3, 5, pl[5]);
        GATE(RV3, RF3, 6, pl[6]); GATE(RV3, RF3, 7, pl[7]);
        GATE(RV3, RF3, 8, pl[8]); GATE(RV3, RF3, 9, pl[9]);
    }
#undef GATE

    // ---- readout: <Z_q> with roles = rows of R^4 (deduped WHT bins) ----
    float pA[16], pB[16];
#pragma unroll
    for (int r = 0; r < 16; ++r) {
        pA[r] = sa[r].x * sa[r].x + sa[r].y * sa[r].y;
        pB[r] = sb[r].x * sb[r].x + sb[r].y * sb[r].y;
    }
#pragma unroll
    for (int m = 1; m < 16; m <<= 1) {
#pragma unroll
        for (int r = 0; r < 16; ++r) {
            if (r & m) continue;
            const float a1 = pA[r], b1 = pA[r | m];
            pA[r] = a1 + b1; pA[r | m] = a1 - b1;
            const float a2 = pB[r], b2 = pB[r | m];
            pB[r] = a2 + b2; pB[r | m] = a2 - b2;
        }
    }
    float wvA[10], wvB[10];
#pragma unroll
    for (int i = 0; i < RB.nbins; ++i) {
        wvA[i] = wht64(pA[RB.bin[i]], lane);
        wvB[i] = wht64(pB[RB.bin[i]], lane);
    }
    const long baseA = (long)b0 * NQ;
    const long baseB = (long)(b0 + 1) * NQ;
#pragma unroll
    for (int q = 0; q < 10; ++q) {
        const int LWq = laneM(RF4.r[q]);
        if (lane == LWq) {
            out[baseA + q] = wvA[RB.q2bin[q]];
            out[baseB + q] = wvB[RB.q2bin[q]];
        }
    }
}

extern "C" void kernel_launch(void* const* d_in, const int* in_sizes, int n_in,
                              void* d_out, int out_size, void* d_ws, size_t ws_size,
                              hipStream_t stream) {
    const float* x = (const float*)d_in[0];       // [B, 10]
    const float* params = (const float*)d_in[1];  // [4, 20]
    float* out = (float*)d_out;                   // [B, 10]
    const int B = in_sizes[0] / NQ;               // 4096
    const int grid = (B + 7) / 8;                 // 4 waves/block, 2 samples/wave
    pqc_kernel<<<grid, 256, 0, stream>>>(x, params, out, B);
}